// Round 1
// baseline (4825.432 us; speedup 1.0000x reference)
//
#include <hip/hip_runtime.h>

#define N_X  40000
#define NN   50000
#define NE   800000

// ---------------- preprocessing ----------------
__global__ void k_deg(const int* __restrict__ dst, int* __restrict__ deg) {
  int e = blockIdx.x * blockDim.x + threadIdx.x;
  if (e < NE) atomicAdd(&deg[dst[e]], 1);
}

__global__ void k_dis(const int* __restrict__ deg, float* __restrict__ dis) {
  int i = blockIdx.x * blockDim.x + threadIdx.x;
  if (i < NN) dis[i] = deg[i] > 0 ? rsqrtf((float)deg[i]) : 0.f;
}

// single-block exclusive scan of deg -> rowp (N+1 entries)
__global__ void k_scan(const int* __restrict__ deg, int* __restrict__ rowp) {
  __shared__ int buf[1024];
  int carry = 0;
  for (int base = 0; base < NN; base += 1024) {
    int i = base + threadIdx.x;
    int v = (i < NN) ? deg[i] : 0;
    buf[threadIdx.x] = v;
    __syncthreads();
    for (int off = 1; off < 1024; off <<= 1) {
      int t = (threadIdx.x >= off) ? buf[threadIdx.x - off] : 0;
      __syncthreads();
      buf[threadIdx.x] += t;
      __syncthreads();
    }
    if (i < NN) rowp[i] = carry + buf[threadIdx.x] - v;
    carry += buf[1023];
    __syncthreads();
  }
  if (threadIdx.x == 0) rowp[NN] = carry;
}

__global__ void k_build(const int* __restrict__ dst, const int* __restrict__ src,
                        const int* __restrict__ typ, const float* __restrict__ dis,
                        const int* __restrict__ rowp, int* __restrict__ cur,
                        unsigned* __restrict__ est, float* __restrict__ ewt) {
  int e = blockIdx.x * blockDim.x + threadIdx.x;
  if (e >= NE) return;
  int d = dst[e], s = src[e];
  int p = rowp[d] + atomicAdd(&cur[d], 1);
  est[p] = (unsigned)s | ((unsigned)typ[e] << 28);
  ewt[p] = dis[d] * dis[s];
}

// ---------------- per-layer kernels ----------------
// layer 0 input: concat(x, emb), raw
__global__ void k_prep0(const float* __restrict__ x, const float* __restrict__ emb,
                        float* __restrict__ X, int xs) {
  int idx = blockIdx.x * blockDim.x + threadIdx.x;
  if (idx >= NN * 128) return;
  int r = idx >> 7, c = idx & 127;
  float v = (r < N_X) ? x[idx] : emb[idx - N_X * 128];
  X[(size_t)r * xs + c] = v;
}

// BN (precomputed scale/shift) + ReLU, H[N][d] -> X[:,0:d]
__global__ void k_prep(const float* __restrict__ H, const float* __restrict__ sc,
                       const float* __restrict__ sh, float* __restrict__ X,
                       int d, int logd, int xs) {
  int idx = blockIdx.x * blockDim.x + threadIdx.x;
  if (idx >= NN * d) return;
  int r = idx >> logd, c = idx & (d - 1);
  float v = H[idx];
  v = fmaxf(v * sc[c] + sh[c], 0.f);
  X[(size_t)r * xs + c] = v;
}

// one block per node; thread = channel; 3 per-relation accumulators
__global__ void k_agg(float* __restrict__ X, const int* __restrict__ rowp,
                      const unsigned* __restrict__ est, const float* __restrict__ ewt,
                      int din, int xs) {
  int n = blockIdx.x;
  int c = threadIdx.x;
  int beg = rowp[n], end = rowp[n + 1];
  float a0 = 0.f, a1 = 0.f, a2 = 0.f;
  for (int i = beg; i < end; ++i) {
    unsigned st = est[i];
    float w = ewt[i];
    int s = (int)(st & 0x0FFFFFFFu);
    unsigned t = st >> 28;
    float v = X[(size_t)s * xs + c];
    float wv = w * v;
    if (t == 0) a0 += wv;
    else if (t == 1) a1 += wv;
    else a2 += wv;
  }
  size_t o = (size_t)n * xs + din + c;
  X[o] = a0;
  X[o + din] = a1;
  X[o + 2 * din] = a2;
}

// Wcat = [root; W0; W1; W2]  (K = 4*din rows, dout cols)
__global__ void k_wcat(const float* __restrict__ root, const float* __restrict__ W,
                       float* __restrict__ Wc, int din, int dout) {
  int idx = blockIdx.x * blockDim.x + threadIdx.x;
  int tot = 4 * din * dout;
  if (idx >= tot) return;
  int k = idx / dout;
  Wc[idx] = (k < din) ? root[idx] : W[idx - din * dout];
}

// f32 tiled GEMM: C[M][Nc] = A[M][K] @ Wc[K][Nc] + bias
#define BM 64
#define BNT 64
#define BK 32
__global__ __launch_bounds__(256) void k_gemm(
    const float* __restrict__ A, const float* __restrict__ Wc,
    const float* __restrict__ bias, float* __restrict__ C,
    int M, int K, int Nc) {
  __shared__ float As[BM][BK + 1];
  __shared__ float Bs[BK][BNT];
  int tid = threadIdx.x;
  int tn = tid & 15, tm = tid >> 4;
  int bm = blockIdx.x * BM, bn = blockIdx.y * BNT;
  float acc[4][4] = {};
  for (int k0 = 0; k0 < K; k0 += BK) {
    {
      int col = tid & 31, r0 = tid >> 5;
#pragma unroll
      for (int it = 0; it < 8; ++it) {
        int m = r0 + it * 8;
        int gm = bm + m;
        As[m][col] = (gm < M) ? A[(size_t)gm * K + k0 + col] : 0.f;
      }
      int nc = tid & 63, kr = tid >> 6;
#pragma unroll
      for (int it = 0; it < 8; ++it) {
        int kk = kr + it * 4;
        Bs[kk][nc] = Wc[(size_t)(k0 + kk) * Nc + bn + nc];
      }
    }
    __syncthreads();
#pragma unroll
    for (int kk = 0; kk < BK; ++kk) {
      float a0 = As[tm * 4 + 0][kk];
      float a1 = As[tm * 4 + 1][kk];
      float a2 = As[tm * 4 + 2][kk];
      float a3 = As[tm * 4 + 3][kk];
      float4 b = *(const float4*)&Bs[kk][tn * 4];
      acc[0][0] += a0 * b.x; acc[0][1] += a0 * b.y; acc[0][2] += a0 * b.z; acc[0][3] += a0 * b.w;
      acc[1][0] += a1 * b.x; acc[1][1] += a1 * b.y; acc[1][2] += a1 * b.z; acc[1][3] += a1 * b.w;
      acc[2][0] += a2 * b.x; acc[2][1] += a2 * b.y; acc[2][2] += a2 * b.z; acc[2][3] += a2 * b.w;
      acc[3][0] += a3 * b.x; acc[3][1] += a3 * b.y; acc[3][2] += a3 * b.z; acc[3][3] += a3 * b.w;
    }
    __syncthreads();
  }
#pragma unroll
  for (int i = 0; i < 4; ++i) {
    int gm = bm + tm * 4 + i;
    if (gm >= M) continue;
    int gn = bn + tn * 4;
    float4 o;
    o.x = acc[i][0] + bias[gn + 0];
    o.y = acc[i][1] + bias[gn + 1];
    o.z = acc[i][2] + bias[gn + 2];
    o.w = acc[i][3] + bias[gn + 3];
    *(float4*)&C[(size_t)gm * Nc + gn] = o;
  }
}

// column sums / sums of squares via per-block register accumulation + atomics
__global__ void k_bnstats(const float* __restrict__ H, float* __restrict__ sums, int d) {
  int c = threadIdx.x;
  float s = 0.f, s2 = 0.f;
  for (int r = blockIdx.x; r < NN; r += gridDim.x) {
    float v = H[(size_t)r * d + c];
    s += v;
    s2 += v * v;
  }
  atomicAdd(&sums[c], s);
  atomicAdd(&sums[d + c], s2);
}

__global__ void k_bnfinal(const float* __restrict__ sums, const float* __restrict__ g,
                          const float* __restrict__ b, float* __restrict__ sc,
                          float* __restrict__ sh, int d) {
  int c = threadIdx.x;
  if (c >= d) return;
  float mean = sums[c] * (1.f / NN);
  float var = sums[d + c] * (1.f / NN) - mean * mean;
  float rs = rsqrtf(var + 1e-5f);
  float s = rs * g[c];
  sc[c] = s;
  sh[c] = b[c] - mean * s;
}

// ---------------- host driver ----------------
extern "C" void kernel_launch(void* const* d_in, const int* in_sizes, int n_in,
                              void* d_out, int out_size, void* d_ws, size_t ws_size,
                              hipStream_t stream) {
  const float* x   = (const float*)d_in[0];
  const float* emb = (const float*)d_in[1];
  const float* conv_w[4] = {(const float*)d_in[2], (const float*)d_in[5],
                            (const float*)d_in[8], (const float*)d_in[11]};
  const float* conv_r[4] = {(const float*)d_in[3], (const float*)d_in[6],
                            (const float*)d_in[9], (const float*)d_in[12]};
  const float* conv_b[4] = {(const float*)d_in[4], (const float*)d_in[7],
                            (const float*)d_in[10], (const float*)d_in[13]};
  const float* n1g = (const float*)d_in[14];
  const float* n1b = (const float*)d_in[15];
  const float* n2g = (const float*)d_in[16];
  const float* n2b = (const float*)d_in[17];
  const int* eidx = (const int*)d_in[18];
  const int* etyp = (const int*)d_in[19];
  const int* dst  = eidx;        // adj_t row = target
  const int* srcp = eidx + NE;   // col = source
  float* out = (float*)d_out;

  char* w = (char*)d_ws;
  auto alloc = [&](size_t bytes) {
    char* p = w;
    w += (bytes + 255) & ~(size_t)255;
    return p;
  };
  float*    X    = (float*)alloc((size_t)NN * 1024 * 4);
  float*    H    = (float*)alloc((size_t)NN * 256 * 4);
  float*    Wc   = (float*)alloc((size_t)1024 * 256 * 4);
  float*    bns  = (float*)alloc(512 * 4);
  float*    bsc  = (float*)alloc(256 * 4);
  float*    bsh  = (float*)alloc(256 * 4);
  float*    dis  = (float*)alloc((size_t)NN * 4);
  int*      deg  = (int*)alloc((size_t)NN * 4);
  int*      rowp = (int*)alloc((size_t)(NN + 1) * 4);
  int*      cur  = (int*)alloc((size_t)NN * 4);
  unsigned* est  = (unsigned*)alloc((size_t)NE * 4);
  float*    ewt  = (float*)alloc((size_t)NE * 4);

  hipMemsetAsync(deg, 0, (size_t)NN * 4, stream);
  hipMemsetAsync(cur, 0, (size_t)NN * 4, stream);
  k_deg<<<(NE + 255) / 256, 256, 0, stream>>>(dst, deg);
  k_dis<<<(NN + 255) / 256, 256, 0, stream>>>(deg, dis);
  k_scan<<<1, 1024, 0, stream>>>(deg, rowp);
  k_build<<<(NE + 255) / 256, 256, 0, stream>>>(dst, srcp, etyp, dis, rowp, cur, est, ewt);

  const int din_a[8]  = {128, 128, 256, 256, 256, 256, 256, 256};
  const int dout_a[8] = {128, 256, 256, 256, 256, 256, 256, 64};
  const int wi_a[8]   = {0, 1, 2, 2, 2, 2, 2, 3};

  for (int l = 0; l < 8; ++l) {
    int din = din_a[l], dout = dout_a[l];
    int K = 4 * din, xs = K;
    int wi = wi_a[l];

    if (l == 0)
      k_prep0<<<(NN * 128 + 255) / 256, 256, 0, stream>>>(x, emb, X, xs);
    else
      k_prep<<<(NN * din + 255) / 256, 256, 0, stream>>>(H, bsc, bsh, X, din,
                                                         (din == 128 ? 7 : 8), xs);

    k_agg<<<NN, din, 0, stream>>>(X, rowp, est, ewt, din, xs);

    k_wcat<<<(K * dout + 255) / 256, 256, 0, stream>>>(conv_r[wi], conv_w[wi], Wc, din, dout);

    float* C = (l == 7) ? out : H;
    dim3 gg((NN + BM - 1) / BM, dout / BNT);
    k_gemm<<<gg, 256, 0, stream>>>(X, Wc, conv_b[wi], C, NN, K, dout);

    if (l < 7) {
      hipMemsetAsync(bns, 0, (size_t)2 * dout * 4, stream);
      k_bnstats<<<256, dout, 0, stream>>>(H, bns, dout);
      k_bnfinal<<<1, 256, 0, stream>>>(bns, (l == 0) ? n1g : n2g,
                                       (l == 0) ? n1b : n2b, bsc, bsh, dout);
    }
  }
}

// Round 2
// 2534.820 us; speedup vs baseline: 1.9037x; 1.9037x over previous
//
#include <hip/hip_runtime.h>

#define N_X  40000
#define NN   50000
#define NE   800000
#define MPAD 50048

using short8  = __attribute__((ext_vector_type(8))) short;
using floatx4 = __attribute__((ext_vector_type(4))) float;
using uintx2  = __attribute__((ext_vector_type(2))) unsigned int;

__device__ __forceinline__ unsigned short f2bf(float f) {
  unsigned u = __float_as_uint(f);
  u += 0x7FFF + ((u >> 16) & 1);           // RNE
  return (unsigned short)(u >> 16);
}
__device__ __forceinline__ float bf2f(unsigned v) {
  return __uint_as_float(v << 16);
}

// ---------------- preprocessing ----------------
__global__ void k_deg(const int* __restrict__ dst, int* __restrict__ deg) {
  int e = blockIdx.x * blockDim.x + threadIdx.x;
  if (e < NE) atomicAdd(&deg[dst[e]], 1);
}

__global__ void k_dis(const int* __restrict__ deg, float* __restrict__ dis) {
  int i = blockIdx.x * blockDim.x + threadIdx.x;
  if (i < NN) dis[i] = deg[i] > 0 ? rsqrtf((float)deg[i]) : 0.f;
}

#define SCAN_B 1024
#define SCAN_NB 49
__global__ void k_scan1(const int* __restrict__ deg, int* __restrict__ rowp,
                        int* __restrict__ bsum) {
  __shared__ int buf[SCAN_B];
  int b = blockIdx.x;
  int i = b * SCAN_B + threadIdx.x;
  int v = (i < NN) ? deg[i] : 0;
  buf[threadIdx.x] = v;
  __syncthreads();
  for (int off = 1; off < SCAN_B; off <<= 1) {
    int t = (threadIdx.x >= off) ? buf[threadIdx.x - off] : 0;
    __syncthreads();
    buf[threadIdx.x] += t;
    __syncthreads();
  }
  if (i < NN) rowp[i] = buf[threadIdx.x] - v;   // block-local exclusive
  if (threadIdx.x == SCAN_B - 1) bsum[b] = buf[SCAN_B - 1];
}

__global__ void k_scan2(int* __restrict__ bsum) {
  if (threadIdx.x == 0) {
    int acc = 0;
    for (int i = 0; i < SCAN_NB; ++i) { int t = bsum[i]; bsum[i] = acc; acc += t; }
  }
}

__global__ void k_scan3(int* __restrict__ rowp, const int* __restrict__ bsum) {
  int i = blockIdx.x * blockDim.x + threadIdx.x;
  if (i < NN) rowp[i] += bsum[i >> 10];
  if (i == 0) rowp[NN] = NE;
}

__global__ void k_build(const int* __restrict__ dst, const int* __restrict__ src,
                        const int* __restrict__ typ, const float* __restrict__ dis,
                        const int* __restrict__ rowp, int* __restrict__ cur,
                        unsigned* __restrict__ est, float* __restrict__ ewt) {
  int e = blockIdx.x * blockDim.x + threadIdx.x;
  if (e >= NE) return;
  int d = dst[e], s = src[e];
  int p = rowp[d] + atomicAdd(&cur[d], 1);
  est[p] = (unsigned)s | ((unsigned)typ[e] << 28);
  ewt[p] = dis[d] * dis[s];
}

// ---------------- per-layer kernels ----------------
__global__ void k_prep0(const float* __restrict__ x, const float* __restrict__ emb,
                        unsigned short* __restrict__ Xh, unsigned short* __restrict__ Xl,
                        int xs) {
  int idx = blockIdx.x * blockDim.x + threadIdx.x;
  if (idx >= NN * 128) return;
  int r = idx >> 7, c = idx & 127;
  float v = (r < N_X) ? x[idx] : emb[idx - N_X * 128];
  unsigned short h = f2bf(v);
  size_t o = (size_t)r * xs + c;
  Xh[o] = h;
  Xl[o] = f2bf(v - bf2f(h));
}

__global__ void k_prep(const float* __restrict__ H, const float* __restrict__ sc,
                       const float* __restrict__ sh, unsigned short* __restrict__ Xh,
                       unsigned short* __restrict__ Xl, int din, int logd, int xs) {
  int idx = blockIdx.x * blockDim.x + threadIdx.x;
  if (idx >= NN * din) return;
  int r = idx >> logd, c = idx & (din - 1);
  float v = fmaxf(H[idx] * sc[c] + sh[c], 0.f);
  unsigned short h = f2bf(v);
  size_t o = (size_t)r * xs + c;
  Xh[o] = h;
  Xl[o] = f2bf(v - bf2f(h));
}

// one WAVE per node; lane covers VEC consecutive channels
template <int VEC>
__global__ void k_agg(unsigned short* __restrict__ Xh, unsigned short* __restrict__ Xl,
                      const int* __restrict__ rowp, const unsigned* __restrict__ est,
                      const float* __restrict__ ewt, int din, int xs) {
  const int wid = (blockIdx.x * 256 + threadIdx.x) >> 6;
  if (wid >= NN) return;
  const int lane = threadIdx.x & 63;
  const int c0 = lane * VEC;
  const int beg = rowp[wid], end = rowp[wid + 1];
  float a0[VEC] = {}, a1[VEC] = {}, a2[VEC] = {};
  for (int i = beg; i < end; ++i) {
    const unsigned st = est[i];
    const float wv = ewt[i];
    const size_t off = (size_t)(st & 0x0FFFFFFFu) * xs + c0;
    const unsigned t = st >> 28;   // wave-uniform
    float v[VEC];
    if constexpr (VEC == 4) {
      uintx2 hr = *(const uintx2*)(Xh + off);
      uintx2 lr = *(const uintx2*)(Xl + off);
      v[0] = bf2f(hr.x & 0xFFFFu) + bf2f(lr.x & 0xFFFFu);
      v[1] = bf2f(hr.x >> 16)     + bf2f(lr.x >> 16);
      v[2] = bf2f(hr.y & 0xFFFFu) + bf2f(lr.y & 0xFFFFu);
      v[3] = bf2f(hr.y >> 16)     + bf2f(lr.y >> 16);
    } else {
      unsigned hr = *(const unsigned*)(Xh + off);
      unsigned lr = *(const unsigned*)(Xl + off);
      v[0] = bf2f(hr & 0xFFFFu) + bf2f(lr & 0xFFFFu);
      v[1] = bf2f(hr >> 16)     + bf2f(lr >> 16);
    }
    if (t == 0) {
#pragma unroll
      for (int q = 0; q < VEC; ++q) a0[q] += wv * v[q];
    } else if (t == 1) {
#pragma unroll
      for (int q = 0; q < VEC; ++q) a1[q] += wv * v[q];
    } else {
#pragma unroll
      for (int q = 0; q < VEC; ++q) a2[q] += wv * v[q];
    }
  }
  const size_t ob = (size_t)wid * xs + din + c0;
  auto store = [&](const float* a, size_t o) {
    unsigned short h[VEC];
    unsigned short lo[VEC];
#pragma unroll
    for (int q = 0; q < VEC; ++q) {
      h[q] = f2bf(a[q]);
      lo[q] = f2bf(a[q] - bf2f(h[q]));
    }
    if constexpr (VEC == 4) {
      uintx2 ph, pl;
      ph.x = (unsigned)h[0] | ((unsigned)h[1] << 16);
      ph.y = (unsigned)h[2] | ((unsigned)h[3] << 16);
      pl.x = (unsigned)lo[0] | ((unsigned)lo[1] << 16);
      pl.y = (unsigned)lo[2] | ((unsigned)lo[3] << 16);
      *(uintx2*)(Xh + o) = ph;
      *(uintx2*)(Xl + o) = pl;
    } else {
      *(unsigned*)(Xh + o) = (unsigned)h[0] | ((unsigned)h[1] << 16);
      *(unsigned*)(Xl + o) = (unsigned)lo[0] | ((unsigned)lo[1] << 16);
    }
  };
  store(a0, ob);
  store(a1, ob + din);
  store(a2, ob + 2 * din);
}

// WcT[n][k] hi/lo, k<din -> root[k][n], else W[k-din][n] (W flat [3*din][dout])
__global__ void k_wcatT(const float* __restrict__ root, const float* __restrict__ W,
                        unsigned short* __restrict__ BhT, unsigned short* __restrict__ BlT,
                        int din, int dout) {
  int idx = blockIdx.x * blockDim.x + threadIdx.x;
  int K = 4 * din;
  if (idx >= dout * K) return;
  int n = idx / K, k = idx % K;
  float v = (k < din) ? root[(size_t)k * dout + n] : W[(size_t)(k - din) * dout + n];
  unsigned short h = f2bf(v);
  BhT[idx] = h;
  BlT[idx] = f2bf(v - bf2f(h));
}

// ---------------- split-f32 MFMA GEMM ----------------
// C[M][Nc] = (Ah+Al)[M][K] @ (Bh+Bl)^T  (B given transposed [Nc][K]) + bias
// tile 128 x BN, 4 waves (2x2), fragment-linear LDS chunks of 1KB
template <int BN>
__global__ __launch_bounds__(256, 2) void k_gemm_mfma(
    const unsigned short* __restrict__ Ah, const unsigned short* __restrict__ Al,
    const unsigned short* __restrict__ Bh, const unsigned short* __restrict__ Bl,
    const float* __restrict__ bias, float* __restrict__ C,
    int M, int K, int Nc) {
  constexpr int NCHB = BN / 16;        // B chunks per plane
  constexpr int TC = 16 + 2 * NCHB;    // total 1KB chunks per buffer
  constexpr int CPW = TC / 4;          // chunks staged per wave
  constexpr int NT = BN / 32;          // n-tiles per wave (waves 2x2)
  __shared__ __align__(16) char lds[2][TC * 1024];

  const int tid = threadIdx.x;
  const int lane = tid & 63;
  const int w = tid >> 6;
  const int wm = w >> 1, wn = w & 1;
  const int bm = blockIdx.x * 128;
  const int bn = blockIdx.y * BN;
  const int r16 = lane & 15, kg = lane >> 4;

  // global fragment source pointers for this wave's staging chunks
  const unsigned short* gcur[CPW];
#pragma unroll
  for (int i = 0; i < CPW; ++i) {
    int c = w * CPW + i;
    const unsigned short* base;
    int row;
    if (c < 8)               { base = Ah; row = bm + c * 16; }
    else if (c < 16)         { base = Al; row = bm + (c - 8) * 16; }
    else if (c < 16 + NCHB)  { base = Bh; row = bn + (c - 16) * 16; }
    else                     { base = Bl; row = bn + (c - 16 - NCHB) * 16; }
    gcur[i] = base + (size_t)(row + r16) * K + kg * 8;
  }

  floatx4 acc[4][NT];
#pragma unroll
  for (int i = 0; i < 4; ++i)
#pragma unroll
    for (int j = 0; j < NT; ++j) acc[i][j] = (floatx4)0.f;

  const int nk = K >> 5;

  // prologue: stage tile 0 via registers
  {
    short8 stg[CPW];
#pragma unroll
    for (int i = 0; i < CPW; ++i) { stg[i] = *(const short8*)gcur[i]; gcur[i] += 32; }
#pragma unroll
    for (int i = 0; i < CPW; ++i)
      *(short8*)&lds[0][(w * CPW + i) * 1024 + lane * 16] = stg[i];
  }
  __syncthreads();

  int buf = 0;
  for (int t = 0; t < nk; ++t) {
    short8 stg[CPW];
    const bool more = (t + 1 < nk);
    if (more) {
#pragma unroll
      for (int i = 0; i < CPW; ++i) { stg[i] = *(const short8*)gcur[i]; gcur[i] += 32; }
    }

    const char* Lb = lds[buf];
    short8 ah[4], al[4], bh[NT], bl[NT];
#pragma unroll
    for (int mt = 0; mt < 4; ++mt) {
      ah[mt] = *(const short8*)(Lb + (wm * 4 + mt) * 1024 + lane * 16);
      al[mt] = *(const short8*)(Lb + (8 + wm * 4 + mt) * 1024 + lane * 16);
    }
#pragma unroll
    for (int nt = 0; nt < NT; ++nt) {
      bh[nt] = *(const short8*)(Lb + (16 + wn * NT + nt) * 1024 + lane * 16);
      bl[nt] = *(const short8*)(Lb + (16 + NCHB + wn * NT + nt) * 1024 + lane * 16);
    }
#pragma unroll
    for (int mt = 0; mt < 4; ++mt)
#pragma unroll
      for (int nt = 0; nt < NT; ++nt) {
        acc[mt][nt] = __builtin_amdgcn_mfma_f32_16x16x32_bf16(ah[mt], bh[nt], acc[mt][nt], 0, 0, 0);
        acc[mt][nt] = __builtin_amdgcn_mfma_f32_16x16x32_bf16(ah[mt], bl[nt], acc[mt][nt], 0, 0, 0);
        acc[mt][nt] = __builtin_amdgcn_mfma_f32_16x16x32_bf16(al[mt], bh[nt], acc[mt][nt], 0, 0, 0);
      }

    if (more) {
      char* Ln = lds[buf ^ 1];
#pragma unroll
      for (int i = 0; i < CPW; ++i)
        *(short8*)&Ln[(w * CPW + i) * 1024 + lane * 16] = stg[i];
    }
    __syncthreads();
    buf ^= 1;
  }

  // epilogue: D row = (lane>>4)*4 + reg, col = lane&15 (measured m89/m91)
#pragma unroll
  for (int mt = 0; mt < 4; ++mt) {
    const int gr0 = bm + wm * 64 + mt * 16 + kg * 4;
#pragma unroll
    for (int nt = 0; nt < NT; ++nt) {
      const int col = bn + wn * (NT * 16) + nt * 16 + r16;
      const float bv = bias[col];
#pragma unroll
      for (int r = 0; r < 4; ++r) {
        const int gr = gr0 + r;
        if (gr < M) C[(size_t)gr * Nc + col] = acc[mt][nt][r] + bv;
      }
    }
  }
}

// ---------------- batch-norm stats ----------------
__global__ void k_bnstats(const float* __restrict__ H, float* __restrict__ sums, int d) {
  int c = threadIdx.x;
  float s = 0.f, s2 = 0.f;
  for (int r = blockIdx.x; r < NN; r += gridDim.x) {
    float v = H[(size_t)r * d + c];
    s += v;
    s2 += v * v;
  }
  atomicAdd(&sums[c], s);
  atomicAdd(&sums[d + c], s2);
}

__global__ void k_bnfinal(const float* __restrict__ sums, const float* __restrict__ g,
                          const float* __restrict__ b, float* __restrict__ sc,
                          float* __restrict__ sh, int d) {
  int c = threadIdx.x;
  if (c >= d) return;
  float mean = sums[c] * (1.f / NN);
  float var = sums[d + c] * (1.f / NN) - mean * mean;
  float rs = rsqrtf(var + 1e-5f);
  float s = rs * g[c];
  sc[c] = s;
  sh[c] = b[c] - mean * s;
}

// ---------------- host driver ----------------
extern "C" void kernel_launch(void* const* d_in, const int* in_sizes, int n_in,
                              void* d_out, int out_size, void* d_ws, size_t ws_size,
                              hipStream_t stream) {
  const float* x   = (const float*)d_in[0];
  const float* emb = (const float*)d_in[1];
  const float* conv_w[4] = {(const float*)d_in[2], (const float*)d_in[5],
                            (const float*)d_in[8], (const float*)d_in[11]};
  const float* conv_r[4] = {(const float*)d_in[3], (const float*)d_in[6],
                            (const float*)d_in[9], (const float*)d_in[12]};
  const float* conv_b[4] = {(const float*)d_in[4], (const float*)d_in[7],
                            (const float*)d_in[10], (const float*)d_in[13]};
  const float* n1g = (const float*)d_in[14];
  const float* n1b = (const float*)d_in[15];
  const float* n2g = (const float*)d_in[16];
  const float* n2b = (const float*)d_in[17];
  const int* eidx = (const int*)d_in[18];
  const int* etyp = (const int*)d_in[19];
  const int* dst  = eidx;        // adj_t row = target
  const int* srcp = eidx + NE;   // col = source
  float* out = (float*)d_out;

  char* w = (char*)d_ws;
  auto alloc = [&](size_t bytes) {
    char* p = w;
    w += (bytes + 255) & ~(size_t)255;
    return p;
  };
  unsigned short* Xh  = (unsigned short*)alloc((size_t)MPAD * 1024 * 2);
  unsigned short* Xl  = (unsigned short*)alloc((size_t)MPAD * 1024 * 2);
  float*    H    = (float*)alloc((size_t)NN * 256 * 4);
  unsigned short* WcTh = (unsigned short*)alloc((size_t)256 * 1024 * 2);
  unsigned short* WcTl = (unsigned short*)alloc((size_t)256 * 1024 * 2);
  float*    bns  = (float*)alloc(512 * 4);
  float*    bsc  = (float*)alloc(256 * 4);
  float*    bsh  = (float*)alloc(256 * 4);
  float*    dis  = (float*)alloc((size_t)NN * 4);
  int*      deg  = (int*)alloc((size_t)NN * 4);
  int*      rowp = (int*)alloc((size_t)(NN + 1) * 4);
  int*      cur  = (int*)alloc((size_t)NN * 4);
  int*      bsum = (int*)alloc(64 * 4);
  unsigned* est  = (unsigned*)alloc((size_t)NE * 4);
  float*    ewt  = (float*)alloc((size_t)NE * 4);

  hipMemsetAsync(deg, 0, (size_t)NN * 4, stream);
  hipMemsetAsync(cur, 0, (size_t)NN * 4, stream);
  k_deg<<<(NE + 255) / 256, 256, 0, stream>>>(dst, deg);
  k_dis<<<(NN + 255) / 256, 256, 0, stream>>>(deg, dis);
  k_scan1<<<SCAN_NB, SCAN_B, 0, stream>>>(deg, rowp, bsum);
  k_scan2<<<1, 64, 0, stream>>>(bsum);
  k_scan3<<<(NN + 255) / 256, 256, 0, stream>>>(rowp, bsum);
  k_build<<<(NE + 255) / 256, 256, 0, stream>>>(dst, srcp, etyp, dis, rowp, cur, est, ewt);

  const int din_a[8]  = {128, 128, 256, 256, 256, 256, 256, 256};
  const int dout_a[8] = {128, 256, 256, 256, 256, 256, 256, 64};
  const int wi_a[8]   = {0, 1, 2, 2, 2, 2, 2, 3};

  for (int l = 0; l < 8; ++l) {
    const int din = din_a[l], dout = dout_a[l];
    const int K = 4 * din, xs = K;
    const int wi = wi_a[l];

    if (l == 0)
      k_prep0<<<(NN * 128 + 255) / 256, 256, 0, stream>>>(x, emb, Xh, Xl, xs);
    else
      k_prep<<<(NN * din + 255) / 256, 256, 0, stream>>>(H, bsc, bsh, Xh, Xl, din,
                                                         (din == 128 ? 7 : 8), xs);

    if (din == 128)
      k_agg<2><<<(NN * 64 + 255) / 256, 256, 0, stream>>>(Xh, Xl, rowp, est, ewt, din, xs);
    else
      k_agg<4><<<(NN * 64 + 255) / 256, 256, 0, stream>>>(Xh, Xl, rowp, est, ewt, din, xs);

    k_wcatT<<<(dout * K + 255) / 256, 256, 0, stream>>>(conv_r[wi], conv_w[wi], WcTh, WcTl, din, dout);

    float* C = (l == 7) ? out : H;
    const int gm = (NN + 127) / 128;
    if (dout == 64)
      k_gemm_mfma<64><<<dim3(gm, 1), 256, 0, stream>>>(Xh, Xl, WcTh, WcTl, conv_b[wi], C, NN, K, dout);
    else
      k_gemm_mfma<128><<<dim3(gm, dout / 128), 256, 0, stream>>>(Xh, Xl, WcTh, WcTl, conv_b[wi], C, NN, K, dout);

    if (l < 7) {
      hipMemsetAsync(bns, 0, (size_t)2 * dout * 4, stream);
      k_bnstats<<<256, dout, 0, stream>>>(H, bns, dout);
      k_bnfinal<<<1, 256, 0, stream>>>(bns, (l == 0) ? n1g : n2g,
                                       (l == 0) ? n1b : n2b, bsc, bsh, dout);
    }
  }
}

// Round 3
// 2409.851 us; speedup vs baseline: 2.0024x; 1.0519x over previous
//
#include <hip/hip_runtime.h>

#define N_X  40000
#define NN   50000
#define NE   800000
#define MPAD 50048

using short8  = __attribute__((ext_vector_type(8))) short;
using floatx4 = __attribute__((ext_vector_type(4))) float;

typedef const __attribute__((address_space(1))) void gv_t;
typedef __attribute__((address_space(3))) void lv_t;

__device__ __forceinline__ unsigned short f2bf(float f) {
  unsigned u = __float_as_uint(f);
  u += 0x7FFF + ((u >> 16) & 1);           // RNE
  return (unsigned short)(u >> 16);
}
__device__ __forceinline__ float bf2f(unsigned v) {
  return __uint_as_float(v << 16);
}

// ---------------- preprocessing ----------------
__global__ void k_deg(const int* __restrict__ dst, int* __restrict__ deg) {
  int e = blockIdx.x * blockDim.x + threadIdx.x;
  if (e < NE) atomicAdd(&deg[dst[e]], 1);
}

__global__ void k_dis(const int* __restrict__ deg, float* __restrict__ dis) {
  int i = blockIdx.x * blockDim.x + threadIdx.x;
  if (i < NN) dis[i] = deg[i] > 0 ? rsqrtf((float)deg[i]) : 0.f;
}

#define SCAN_B 1024
#define SCAN_NB 49
__global__ void k_scan1(const int* __restrict__ deg, int* __restrict__ rowp,
                        int* __restrict__ bsum) {
  __shared__ int buf[SCAN_B];
  int b = blockIdx.x;
  int i = b * SCAN_B + threadIdx.x;
  int v = (i < NN) ? deg[i] : 0;
  buf[threadIdx.x] = v;
  __syncthreads();
  for (int off = 1; off < SCAN_B; off <<= 1) {
    int t = (threadIdx.x >= off) ? buf[threadIdx.x - off] : 0;
    __syncthreads();
    buf[threadIdx.x] += t;
    __syncthreads();
  }
  if (i < NN) rowp[i] = buf[threadIdx.x] - v;   // block-local exclusive
  if (threadIdx.x == SCAN_B - 1) bsum[b] = buf[SCAN_B - 1];
}

__global__ void k_scan2(int* __restrict__ bsum) {
  if (threadIdx.x == 0) {
    int acc = 0;
    for (int i = 0; i < SCAN_NB; ++i) { int t = bsum[i]; bsum[i] = acc; acc += t; }
  }
}

__global__ void k_scan3(int* __restrict__ rowp, const int* __restrict__ bsum) {
  int i = blockIdx.x * blockDim.x + threadIdx.x;
  if (i < NN) rowp[i] += bsum[i >> 10];
  if (i == 0) rowp[NN] = NE;
}

__global__ void k_build(const int* __restrict__ dst, const int* __restrict__ src,
                        const int* __restrict__ typ, const float* __restrict__ dis,
                        const int* __restrict__ rowp, int* __restrict__ cur,
                        unsigned* __restrict__ est, float* __restrict__ ewt) {
  int e = blockIdx.x * blockDim.x + threadIdx.x;
  if (e >= NE) return;
  int d = dst[e], s = src[e];
  int p = rowp[d] + atomicAdd(&cur[d], 1);
  est[p] = (unsigned)s | ((unsigned)typ[e] << 28);
  ewt[p] = dis[d] * dis[s];
}

// ---------------- per-layer kernels ----------------
// layer 0 input: concat(x, emb) -> hi/lo planes, 4 channels per thread
__global__ void k_prep0(const float* __restrict__ x, const float* __restrict__ emb,
                        unsigned short* __restrict__ Xh, unsigned short* __restrict__ Xl,
                        int xs) {
  int idx = blockIdx.x * blockDim.x + threadIdx.x;
  if (idx >= NN * 32) return;
  int r = idx >> 5, c4 = (idx & 31) * 4;
  const float* srcp = (r < N_X) ? (x + (size_t)r * 128 + c4)
                                : (emb + (size_t)(r - N_X) * 128 + c4);
  float4 hv = *(const float4*)srcp;
  float vv[4] = {hv.x, hv.y, hv.z, hv.w};
  unsigned hw[2], lw[2];
#pragma unroll
  for (int q = 0; q < 2; ++q) {
    unsigned short h0 = f2bf(vv[2 * q]), h1 = f2bf(vv[2 * q + 1]);
    unsigned short l0 = f2bf(vv[2 * q] - bf2f(h0)), l1 = f2bf(vv[2 * q + 1] - bf2f(h1));
    hw[q] = (unsigned)h0 | ((unsigned)h1 << 16);
    lw[q] = (unsigned)l0 | ((unsigned)l1 << 16);
  }
  size_t o = (size_t)r * xs + c4;
  *(uint2*)(Xh + o) = make_uint2(hw[0], hw[1]);
  *(uint2*)(Xl + o) = make_uint2(lw[0], lw[1]);
}

// BN (precomputed scale/shift) + ReLU, 4 channels per thread
__global__ void k_prep(const float* __restrict__ H, const float* __restrict__ sc,
                       const float* __restrict__ sh, unsigned short* __restrict__ Xh,
                       unsigned short* __restrict__ Xl, int din, int logq, int xs) {
  int idx = blockIdx.x * blockDim.x + threadIdx.x;
  if (idx >= NN * (din >> 2)) return;
  int r = idx >> logq, c4 = (idx & ((din >> 2) - 1)) * 4;
  float4 hv = *(const float4*)(H + (size_t)r * din + c4);
  float vv[4] = {hv.x, hv.y, hv.z, hv.w};
  unsigned hw[2], lw[2];
#pragma unroll
  for (int q = 0; q < 4; ++q)
    vv[q] = fmaxf(vv[q] * sc[c4 + q] + sh[c4 + q], 0.f);
#pragma unroll
  for (int q = 0; q < 2; ++q) {
    unsigned short h0 = f2bf(vv[2 * q]), h1 = f2bf(vv[2 * q + 1]);
    unsigned short l0 = f2bf(vv[2 * q] - bf2f(h0)), l1 = f2bf(vv[2 * q + 1] - bf2f(h1));
    hw[q] = (unsigned)h0 | ((unsigned)h1 << 16);
    lw[q] = (unsigned)l0 | ((unsigned)l1 << 16);
  }
  size_t o = (size_t)r * xs + c4;
  *(uint2*)(Xh + o) = make_uint2(hw[0], hw[1]);
  *(uint2*)(Xl + o) = make_uint2(lw[0], lw[1]);
}

// one WAVE per node; L lanes per edge (L = din/8), 64/L edges in flight
template <int L>
__global__ void k_agg(unsigned short* __restrict__ Xh, unsigned short* __restrict__ Xl,
                      const int* __restrict__ rowp, const unsigned* __restrict__ est,
                      const float* __restrict__ ewt, int xs) {
  constexpr int G = 64 / L;
  constexpr int din = L * 8;
  const int wid = (blockIdx.x * 256 + threadIdx.x) >> 6;
  if (wid >= NN) return;
  const int lane = threadIdx.x & 63;
  const int grp = lane / L;
  const int j = lane & (L - 1);
  const int c0 = j * 8;
  const int beg = rowp[wid], end = rowp[wid + 1];
  float a0[8] = {}, a1[8] = {}, a2[8] = {};
  for (int i = beg + grp; i < end; i += G) {
    const unsigned st = est[i];
    const float wv = ewt[i];
    const size_t off = (size_t)(st & 0x0FFFFFFFu) * xs + c0;
    const unsigned t = st >> 28;
    uint4 hr = *(const uint4*)(Xh + off);
    uint4 lr = *(const uint4*)(Xl + off);
    float v[8];
    v[0] = bf2f(hr.x & 0xFFFFu) + bf2f(lr.x & 0xFFFFu);
    v[1] = bf2f(hr.x >> 16)     + bf2f(lr.x >> 16);
    v[2] = bf2f(hr.y & 0xFFFFu) + bf2f(lr.y & 0xFFFFu);
    v[3] = bf2f(hr.y >> 16)     + bf2f(lr.y >> 16);
    v[4] = bf2f(hr.z & 0xFFFFu) + bf2f(lr.z & 0xFFFFu);
    v[5] = bf2f(hr.z >> 16)     + bf2f(lr.z >> 16);
    v[6] = bf2f(hr.w & 0xFFFFu) + bf2f(lr.w & 0xFFFFu);
    v[7] = bf2f(hr.w >> 16)     + bf2f(lr.w >> 16);
    if (t == 0) {
#pragma unroll
      for (int q = 0; q < 8; ++q) a0[q] += wv * v[q];
    } else if (t == 1) {
#pragma unroll
      for (int q = 0; q < 8; ++q) a1[q] += wv * v[q];
    } else {
#pragma unroll
      for (int q = 0; q < 8; ++q) a2[q] += wv * v[q];
    }
  }
  // reduce across the G edge-groups (lanes with same j)
#pragma unroll
  for (int off = L; off < 64; off <<= 1) {
#pragma unroll
    for (int q = 0; q < 8; ++q) {
      a0[q] += __shfl_xor(a0[q], off);
      a1[q] += __shfl_xor(a1[q], off);
      a2[q] += __shfl_xor(a2[q], off);
    }
  }
  if (grp == 0) {
    const size_t ob = (size_t)wid * xs + din + c0;
    auto store8 = [&](const float* a, size_t o) {
      unsigned hw[4], lw[4];
#pragma unroll
      for (int q = 0; q < 4; ++q) {
        unsigned short h0 = f2bf(a[2 * q]), h1 = f2bf(a[2 * q + 1]);
        unsigned short l0 = f2bf(a[2 * q] - bf2f(h0)), l1 = f2bf(a[2 * q + 1] - bf2f(h1));
        hw[q] = (unsigned)h0 | ((unsigned)h1 << 16);
        lw[q] = (unsigned)l0 | ((unsigned)l1 << 16);
      }
      *(uint4*)(Xh + o) = make_uint4(hw[0], hw[1], hw[2], hw[3]);
      *(uint4*)(Xl + o) = make_uint4(lw[0], lw[1], lw[2], lw[3]);
    };
    store8(a0, ob);
    store8(a1, ob + din);
    store8(a2, ob + 2 * din);
  }
}

// WcT[n][k] hi/lo, k<din -> root[k][n], else W[k-din][n]
__global__ void k_wcatT(const float* __restrict__ root, const float* __restrict__ W,
                        unsigned short* __restrict__ BhT, unsigned short* __restrict__ BlT,
                        int din, int dout) {
  int idx = blockIdx.x * blockDim.x + threadIdx.x;
  int K = 4 * din;
  if (idx >= dout * K) return;
  int n = idx / K, k = idx % K;
  float v = (k < din) ? root[(size_t)k * dout + n] : W[(size_t)(k - din) * dout + n];
  unsigned short h = f2bf(v);
  BhT[idx] = h;
  BlT[idx] = f2bf(v - bf2f(h));
}

// ---------------- split-f32 MFMA GEMM ----------------
// C = (Ah+Al) @ (Bh+Bl)^T + bias, tile 128 x BN, 4 waves (2x2)
// global_load_lds staging (wave-uniform LDS base + lane*16), 2-phase pipeline
template <int BN>
__global__ __launch_bounds__(256, 2) void k_gemm_mfma(
    const unsigned short* __restrict__ Ah, const unsigned short* __restrict__ Al,
    const unsigned short* __restrict__ Bh, const unsigned short* __restrict__ Bl,
    const float* __restrict__ bias, float* __restrict__ C,
    int M, int K, int Nc, int ny) {
  constexpr int NCHB = BN / 16;        // B chunks per plane
  constexpr int TC = 16 + 2 * NCHB;    // 1KB chunks per buffer
  constexpr int CPW = TC / 4;          // chunks staged per wave
  constexpr int NT = BN / 32;          // n-frags per wave
  __shared__ __align__(16) char lds[2][TC * 1024];

  const int tid = threadIdx.x;
  const int lane = tid & 63;
  const int w = tid >> 6;
  const int wm = w >> 1, wn = w & 1;
  const int r16 = lane & 15, kg = lane >> 4;

  // bijective XCD swizzle (m204): contiguous logical chunk per XCD
  const int nwg = gridDim.x;
  const int q = nwg >> 3, r = nwg & 7;
  const int xcd = blockIdx.x & 7, pos = blockIdx.x >> 3;
  const int t = (xcd < r ? xcd * (q + 1) : r * (q + 1) + (xcd - r) * q) + pos;
  const int bm = (t / ny) * 128;
  const int bn = (t % ny) * BN;

  // per-lane global source addresses for this wave's staging chunks
  const unsigned short* gb[CPW];
#pragma unroll
  for (int i = 0; i < CPW; ++i) {
    int c = w * CPW + i;
    const unsigned short* base;
    int row;
    if (c < 8)               { base = Ah; row = bm + c * 16; }
    else if (c < 16)         { base = Al; row = bm + (c - 8) * 16; }
    else if (c < 16 + NCHB)  { base = Bh; row = bn + (c - 16) * 16; }
    else                     { base = Bl; row = bn + (c - 16 - NCHB) * 16; }
    gb[i] = base + (size_t)(row + r16) * K + kg * 8;
  }

  floatx4 acc[4][NT];
#pragma unroll
  for (int i = 0; i < 4; ++i)
#pragma unroll
    for (int jj = 0; jj < NT; ++jj) acc[i][jj] = (floatx4)0.f;

  const int nk = K >> 5;

  auto stage = [&](int b, int tk) {
#pragma unroll
    for (int i = 0; i < CPW; ++i)
      __builtin_amdgcn_global_load_lds((gv_t*)(gb[i] + tk * 32),
                                       (lv_t*)&lds[b][(w * CPW + i) * 1024],
                                       16, 0, 0);
  };

  stage(0, 0);
  asm volatile("s_waitcnt vmcnt(0)" ::: "memory");
  __builtin_amdgcn_s_barrier();

  int buf = 0;
  for (int tk = 0; tk < nk; ++tk) {
    if (tk + 1 < nk) stage(buf ^ 1, tk + 1);

    const char* Lb = lds[buf];
    short8 ah[4], al[4], bh[NT], bl[NT];
#pragma unroll
    for (int mt = 0; mt < 4; ++mt) {
      ah[mt] = *(const short8*)(Lb + (wm * 4 + mt) * 1024 + lane * 16);
      al[mt] = *(const short8*)(Lb + (8 + wm * 4 + mt) * 1024 + lane * 16);
    }
#pragma unroll
    for (int nt = 0; nt < NT; ++nt) {
      bh[nt] = *(const short8*)(Lb + (16 + wn * NT + nt) * 1024 + lane * 16);
      bl[nt] = *(const short8*)(Lb + (16 + NCHB + wn * NT + nt) * 1024 + lane * 16);
    }
#pragma unroll
    for (int mt = 0; mt < 4; ++mt)
#pragma unroll
      for (int nt = 0; nt < NT; ++nt) {
        acc[mt][nt] = __builtin_amdgcn_mfma_f32_16x16x32_bf16(ah[mt], bh[nt], acc[mt][nt], 0, 0, 0);
        acc[mt][nt] = __builtin_amdgcn_mfma_f32_16x16x32_bf16(ah[mt], bl[nt], acc[mt][nt], 0, 0, 0);
        acc[mt][nt] = __builtin_amdgcn_mfma_f32_16x16x32_bf16(al[mt], bh[nt], acc[mt][nt], 0, 0, 0);
      }

    asm volatile("s_waitcnt vmcnt(0)" ::: "memory");
    __builtin_amdgcn_s_barrier();
    buf ^= 1;
  }

  // D row = (lane>>4)*4 + reg, col = lane&15
#pragma unroll
  for (int mt = 0; mt < 4; ++mt) {
    const int gr0 = bm + wm * 64 + mt * 16 + kg * 4;
#pragma unroll
    for (int nt = 0; nt < NT; ++nt) {
      const int col = bn + wn * (NT * 16) + nt * 16 + r16;
      const float bv = bias[col];
#pragma unroll
      for (int rr = 0; rr < 4; ++rr) {
        const int gr = gr0 + rr;
        if (gr < M) C[(size_t)gr * Nc + col] = acc[mt][nt][rr] + bv;
      }
    }
  }
}

// ---------------- batch-norm stats ----------------
__global__ void k_bnstats(const float* __restrict__ H, float* __restrict__ sums, int d) {
  int c = threadIdx.x;
  float s = 0.f, s2 = 0.f;
  for (int r = blockIdx.x; r < NN; r += gridDim.x) {
    float v = H[(size_t)r * d + c];
    s += v;
    s2 += v * v;
  }
  atomicAdd(&sums[c], s);
  atomicAdd(&sums[d + c], s2);
}

__global__ void k_bnfinal(const float* __restrict__ sums, const float* __restrict__ g,
                          const float* __restrict__ b, float* __restrict__ sc,
                          float* __restrict__ sh, int d) {
  int c = threadIdx.x;
  if (c >= d) return;
  float mean = sums[c] * (1.f / NN);
  float var = sums[d + c] * (1.f / NN) - mean * mean;
  float rs = rsqrtf(var + 1e-5f);
  float s = rs * g[c];
  sc[c] = s;
  sh[c] = b[c] - mean * s;
}

// ---------------- host driver ----------------
extern "C" void kernel_launch(void* const* d_in, const int* in_sizes, int n_in,
                              void* d_out, int out_size, void* d_ws, size_t ws_size,
                              hipStream_t stream) {
  const float* x   = (const float*)d_in[0];
  const float* emb = (const float*)d_in[1];
  const float* conv_w[4] = {(const float*)d_in[2], (const float*)d_in[5],
                            (const float*)d_in[8], (const float*)d_in[11]};
  const float* conv_r[4] = {(const float*)d_in[3], (const float*)d_in[6],
                            (const float*)d_in[9], (const float*)d_in[12]};
  const float* conv_b[4] = {(const float*)d_in[4], (const float*)d_in[7],
                            (const float*)d_in[10], (const float*)d_in[13]};
  const float* n1g = (const float*)d_in[14];
  const float* n1b = (const float*)d_in[15];
  const float* n2g = (const float*)d_in[16];
  const float* n2b = (const float*)d_in[17];
  const int* eidx = (const int*)d_in[18];
  const int* etyp = (const int*)d_in[19];
  const int* dst  = eidx;        // adj_t row = target
  const int* srcp = eidx + NE;   // col = source
  float* out = (float*)d_out;

  char* w = (char*)d_ws;
  auto alloc = [&](size_t bytes) {
    char* p = w;
    w += (bytes + 255) & ~(size_t)255;
    return p;
  };
  unsigned short* Xh  = (unsigned short*)alloc((size_t)MPAD * 1024 * 2);
  unsigned short* Xl  = (unsigned short*)alloc((size_t)MPAD * 1024 * 2);
  float*    H    = (float*)alloc((size_t)NN * 256 * 4);
  unsigned short* WcTh = (unsigned short*)alloc((size_t)256 * 1024 * 2);
  unsigned short* WcTl = (unsigned short*)alloc((size_t)256 * 1024 * 2);
  float*    bns  = (float*)alloc(512 * 4);
  float*    bsc  = (float*)alloc(256 * 4);
  float*    bsh  = (float*)alloc(256 * 4);
  float*    dis  = (float*)alloc((size_t)NN * 4);
  int*      deg  = (int*)alloc((size_t)NN * 4);
  int*      rowp = (int*)alloc((size_t)(NN + 1) * 4);
  int*      cur  = (int*)alloc((size_t)NN * 4);
  int*      bsum = (int*)alloc(64 * 4);
  unsigned* est  = (unsigned*)alloc((size_t)NE * 4);
  float*    ewt  = (float*)alloc((size_t)NE * 4);

  hipMemsetAsync(deg, 0, (size_t)NN * 4, stream);
  hipMemsetAsync(cur, 0, (size_t)NN * 4, stream);
  k_deg<<<(NE + 255) / 256, 256, 0, stream>>>(dst, deg);
  k_dis<<<(NN + 255) / 256, 256, 0, stream>>>(deg, dis);
  k_scan1<<<SCAN_NB, SCAN_B, 0, stream>>>(deg, rowp, bsum);
  k_scan2<<<1, 64, 0, stream>>>(bsum);
  k_scan3<<<(NN + 255) / 256, 256, 0, stream>>>(rowp, bsum);
  k_build<<<(NE + 255) / 256, 256, 0, stream>>>(dst, srcp, etyp, dis, rowp, cur, est, ewt);

  const int din_a[8]  = {128, 128, 256, 256, 256, 256, 256, 256};
  const int dout_a[8] = {128, 256, 256, 256, 256, 256, 256, 64};
  const int wi_a[8]   = {0, 1, 2, 2, 2, 2, 2, 3};
  const int gm = (NN + 127) / 128;   // 391

  for (int l = 0; l < 8; ++l) {
    const int din = din_a[l], dout = dout_a[l];
    const int K = 4 * din, xs = K;
    const int wi = wi_a[l];

    if (l == 0)
      k_prep0<<<(NN * 32 + 255) / 256, 256, 0, stream>>>(x, emb, Xh, Xl, xs);
    else
      k_prep<<<(NN * (din >> 2) + 255) / 256, 256, 0, stream>>>(
          H, bsc, bsh, Xh, Xl, din, (din == 128 ? 5 : 6), xs);

    if (din == 128)
      k_agg<16><<<(NN + 3) / 4, 256, 0, stream>>>(Xh, Xl, rowp, est, ewt, xs);
    else
      k_agg<32><<<(NN + 3) / 4, 256, 0, stream>>>(Xh, Xl, rowp, est, ewt, xs);

    k_wcatT<<<(dout * K + 255) / 256, 256, 0, stream>>>(conv_r[wi], conv_w[wi], WcTh, WcTl, din, dout);

    float* C = (l == 7) ? out : H;
    if (dout == 64)
      k_gemm_mfma<64><<<gm, 256, 0, stream>>>(Xh, Xl, WcTh, WcTl, conv_b[wi], C, NN, K, dout, 1);
    else if (dout == 128)
      k_gemm_mfma<128><<<gm, 256, 0, stream>>>(Xh, Xl, WcTh, WcTl, conv_b[wi], C, NN, K, dout, 1);
    else
      k_gemm_mfma<128><<<gm * 2, 256, 0, stream>>>(Xh, Xl, WcTh, WcTl, conv_b[wi], C, NN, K, dout, 2);

    if (l < 7) {
      hipMemsetAsync(bns, 0, (size_t)2 * dout * 4, stream);
      k_bnstats<<<256, dout, 0, stream>>>(H, bns, dout);
      k_bnfinal<<<1, 256, 0, stream>>>(bns, (l == 0) ? n1g : n2g,
                                       (l == 0) ? n1b : n2b, bsc, bsh, dout);
    }
  }
}